// Round 20
// baseline (2909.287 us; speedup 1.0000x reference)
//
#include <hip/hip_runtime.h>

#define BB 64
#define HH 1024
#define TT 512
#define GG 4096
#define VV 256
#define NBLK 256
#define BPG 128   // blocks per group
#define BG  32    // batches per group
#define UPB 8     // units per block
#define SLOT (BB * HH)        // 65536 elements per h slot
#define GREG 32768            // elements per group region within a slot

typedef __attribute__((ext_vector_type(8))) short short8;
typedef __attribute__((ext_vector_type(4))) float f32x4;
typedef __attribute__((ext_vector_type(4))) unsigned uint32x4;

__device__ __forceinline__ unsigned short f2bf(float f) {
  unsigned u = __float_as_uint(f);
  u += 0x7fffu + ((u >> 16) & 1u);
  return (unsigned short)(u >> 16);
}

__device__ __forceinline__ float sigf(float x) { return 1.0f / (1.0f + __expf(-x)); }
__device__ __forceinline__ float tanhfast(float x) {
  float t = __expf(2.0f * x);
  return (t - 1.0f) / (t + 1.0f);
}

__device__ __forceinline__ unsigned pkmax(unsigned a, unsigned b) {
  unsigned d;
  asm("v_pk_max_u16 %0, %1, %2" : "=v"(d) : "v"(a), "v"(b));
  return d;
}

__device__ __forceinline__ bool anypoison(uint32x4 a, uint32x4 b) {
  const unsigned mm = pkmax(pkmax(pkmax(a[0], a[1]), pkmax(a[2], a[3])),
                            pkmax(pkmax(b[0], b[1]), pkmax(b[2], b[3])));
  return ((mm & 0xFFFFu) == 0xFFFFu) || ((mm >> 16) == 0xFFFFu);
}

__device__ __forceinline__ short8 as_s8(uint32x4 v) {
  short8 r;
  __builtin_memcpy(&r, &v, 16);
  return r;
}

// ---------------------------------------------------------------------------
// Prepass 1: P0[v][unit][gate] = (embed @ Wi[0] + b[0]) re-packed, fp32.
// ---------------------------------------------------------------------------
__global__ void __launch_bounds__(256, 1)
p0_kernel(const float* __restrict__ embed, const float* __restrict__ Wi,
          const float* __restrict__ bias, float* __restrict__ P0p)
{
  __shared__ float elds[16][1024];  // 64 KB
  const int tid = threadIdx.x;
  const int vt = blockIdx.x >> 4;
  const int ct = blockIdx.x & 15;
  for (int i = tid; i < 16 * 1024; i += 256)
    elds[i >> 10][i & 1023] = embed[((vt * 16 + (i >> 10)) << 10) + (i & 1023)];
  __syncthreads();
  const int c = ct * 256 + tid;           // column in [0,4096)
  float acc[16];
#pragma unroll
  for (int v = 0; v < 16; ++v) acc[v] = 0.f;
  for (int kk = 0; kk < 1024; ++kk) {
    const float wv = Wi[kk * GG + c];     // coalesced
#pragma unroll
    for (int v = 0; v < 16; ++v) acc[v] = fmaf(elds[v][kk], wv, acc[v]);
  }
  const int u = c & 1023, g = c >> 10;
  const float bv = bias[c];               // b[0][c]
#pragma unroll
  for (int v = 0; v < 16; ++v)
    P0p[(((size_t)(vt * 16 + v) * HH) + u) * 4 + g] = acc[v] + bv;
}

// ---------------------------------------------------------------------------
// Prepass 2: pack Wproj into bf16 MFMA B-fragments; pack b[1] as [unit][gate].
// ---------------------------------------------------------------------------
__global__ void pack_misc(const float* __restrict__ Wproj, const float* __restrict__ bias,
                          unsigned short* __restrict__ Wppk, float* __restrict__ b1p)
{
  const int t = blockIdx.x * 256 + threadIdx.x;
  if (t < 16 * 32 * 64) {
    const int lane = t & 63;
    const int kt = (t >> 6) & 31;
    const int nt = t >> 11;
    const int v = nt * 16 + (lane & 15);
    const int kb = kt * 32 + (lane >> 4) * 8;
    short8 fr;
#pragma unroll
    for (int e = 0; e < 8; ++e)
      fr[e] = (short)f2bf(Wproj[(size_t)(kb + e) * VV + v]);
    *(short8*)(Wppk + (size_t)t * 8) = fr;
  }
  if (t < 4096)
    b1p[t] = bias[GG + (t & 3) * HH + (t >> 2)];  // b1p[u*4+g] = b[1][g*1024+u]
}

// ---------------------------------------------------------------------------
// Persistent LSTM kernel: split-phase data-poll, pipelined ring issue.
// r19's early re-poll REVERTED (it exposed ringB flight RT: -0.5us/tick).
// NEW: ringA (h0, slot k+1) issue moved from tick end to right after the
// ringB scan — its ~0.9us flight now hides under A2+gates1+h1-store instead
// of being exposed at the next tick's step-2 wait. vmcnt accounting at
// step 2 unchanged (drains ringA+prefetch+h1store; leaves the 16 new ringB).
// Poison protocol: h rotates write-once, pre-poisoned 0xFFFF (bf16 NaN);
// polls sc0 sc1 (L2-bypass). REGIONED layout (r13): full-line single-
// producer write-through stores from wave 0.
// ---------------------------------------------------------------------------
__global__ void __launch_bounds__(256, 1)
lstm_persist(const float* __restrict__ Wi, const float* __restrict__ Wh,
             const int* __restrict__ idx, const float* __restrict__ P0p,
             const float* __restrict__ b1p,
             unsigned short* __restrict__ h0r, unsigned short* __restrict__ hs)
{
  __shared__ short wlds[32][2][64][8];      // 64 KB: Wh0 [kt][nt][lane][8]
  __shared__ float zbuf[2][4][32][36];      // 36 KB
  __shared__ unsigned short hstage[2][256]; // 1 KB

  const int tid = threadIdx.x;
  const int lane = tid & 63;
  const int w = tid >> 6;
  const int bid = blockIdx.x;
  const int g = bid & 1;          // group (~XCD parity)
  const int ub = bid >> 1;        // unit-block 0..127
  const int w8 = w * 8;

  // ---- one-time: Wh0 fragments -> LDS; Wi1, Wh1 fragments -> VGPRs ----
  short8 wi1r[8][2], wh1r[8][2];
  {
    const int arow16 = lane & 15;
    const int kb4 = (lane >> 4) * 8;
    for (int kk = 0; kk < 8; ++kk) {
      const int kbase = (w8 + kk) * 32 + kb4;
      for (int nt = 0; nt < 2; ++nt) {
        const int cl = nt * 16 + arow16;
        const int cg = (cl & 3) * HH + ub * UPB + (cl >> 2);
        short8 fr;
#pragma unroll
        for (int e = 0; e < 8; ++e)
          fr[e] = (short)f2bf(Wh[(size_t)(kbase + e) * GG + cg]);
        *(short8*)(&wlds[w8 + kk][nt][lane][0]) = fr;
      }
    }
    const float* srcWi1 = Wi + (size_t)HH * GG;
    const float* srcWh1 = Wh + (size_t)HH * GG;
#pragma unroll
    for (int kk = 0; kk < 8; ++kk) {
      const int kbase = (w8 + kk) * 32 + kb4;
#pragma unroll
      for (int nt = 0; nt < 2; ++nt) {
        const int cl = nt * 16 + arow16;
        const int cg = (cl & 3) * HH + ub * UPB + (cl >> 2);
        short8 fa, fb;
#pragma unroll
        for (int e = 0; e < 8; ++e) {
          fa[e] = (short)f2bf(srcWi1[(size_t)(kbase + e) * GG + cg]);
          fb[e] = (short)f2bf(srcWh1[(size_t)(kbase + e) * GG + cg]);
        }
        wi1r[kk][nt] = fa;
        wh1r[kk][nt] = fb;
      }
    }
  }
  __syncthreads();

  const int ebl = tid >> 3;            // 0..31
  const int eu = tid & 7;              // 0..7
  const int ebg = g * BG + ebl;        // global batch row
  const int egu = ub * UPB + eu;       // global unit
  float c0 = 0.f, c1 = 0.f;
  const float4 b1v = *(const float4*)(b1p + egu * 4);

  const int arow = lane & 15;
  // regioned A offsets within a slot (r13 layout)
  const int ro0 = g * GREG + w8 * 1024 + (lane >> 4) * 256 + arow * 8;
  const int ro1 = ro0 + 128;

  int v_pf = idx[ebg * TT];                                        // k = 0
  float4 p_pf = *(const float4*)(P0p + ((size_t)v_pf * HH + egu) * 4);

#define GLDP(dst, addr)                                                        \
  asm volatile("global_load_dwordx4 %0, %1, off sc0 sc1"                       \
               : "=&v"(dst) : "v"(addr));

#define WAITI(n)                                                               \
  asm volatile("s_waitcnt vmcnt(" #n ")" ::: "memory");                        \
  __builtin_amdgcn_sched_barrier(0);

#define LDB(s, nt) (*(const short8*)(&wlds[w8 + (s)][nt][lane][0]))

#define ISSUE_RING(rg, pa, pb)                                                 \
  GLDP(rg[0][0], (pa) + 0 * 1024) GLDP(rg[0][1], (pb) + 0 * 1024)              \
  GLDP(rg[1][0], (pa) + 1 * 1024) GLDP(rg[1][1], (pb) + 1 * 1024)              \
  GLDP(rg[2][0], (pa) + 2 * 1024) GLDP(rg[2][1], (pb) + 2 * 1024)              \
  GLDP(rg[3][0], (pa) + 3 * 1024) GLDP(rg[3][1], (pb) + 3 * 1024)              \
  GLDP(rg[4][0], (pa) + 4 * 1024) GLDP(rg[4][1], (pb) + 4 * 1024)              \
  GLDP(rg[5][0], (pa) + 5 * 1024) GLDP(rg[5][1], (pb) + 5 * 1024)              \
  GLDP(rg[6][0], (pa) + 6 * 1024) GLDP(rg[6][1], (pb) + 6 * 1024)              \
  GLDP(rg[7][0], (pa) + 7 * 1024) GLDP(rg[7][1], (pb) + 7 * 1024)

#define CHKR(rg, s)                                                            \
  if (need & (1u << (s))) {                                                    \
    if (__any(anypoison(rg[s][0], rg[s][1]))) nneed |= (1u << (s));            \
  }

#define REISS(rg, s, pa, pb)                                                   \
  if (need & (1u << (s))) {                                                    \
    GLDP(rg[s][0], (pa) + (s) * 1024)                                          \
    GLDP(rg[s][1], (pb) + (s) * 1024)                                          \
  }

// initial scan + bounded retry loop (first retry immediate, then sleep)
#define SCANLOOP(rg, pa, pb)                                                   \
  {                                                                            \
    unsigned need = 0xFFu;                                                     \
    {                                                                          \
      unsigned nneed = 0;                                                      \
      CHKR(rg, 0) CHKR(rg, 1) CHKR(rg, 2) CHKR(rg, 3)                          \
      CHKR(rg, 4) CHKR(rg, 5) CHKR(rg, 6) CHKR(rg, 7)                          \
      need = nneed;                                                            \
    }                                                                          \
    int tries = 0;                                                             \
    while (need) {                                                             \
      if (++tries > (1 << 17)) break;  /* safety valve */                      \
      if (tries > 1) __builtin_amdgcn_s_sleep(4);                              \
      REISS(rg, 0, pa, pb) REISS(rg, 1, pa, pb) REISS(rg, 2, pa, pb)           \
      REISS(rg, 3, pa, pb) REISS(rg, 4, pa, pb) REISS(rg, 5, pa, pb)           \
      REISS(rg, 6, pa, pb) REISS(rg, 7, pa, pb)                                \
      WAITI(0)                                                                 \
      unsigned nneed = 0;                                                      \
      CHKR(rg, 0) CHKR(rg, 1) CHKR(rg, 2) CHKR(rg, 3)                          \
      CHKR(rg, 4) CHKR(rg, 5) CHKR(rg, 6) CHKR(rg, 7)                          \
      need = nneed;                                                            \
    }                                                                          \
    __builtin_amdgcn_sched_barrier(0);                                         \
  }

#define STAGE_A01(s)                                                           \
  {                                                                            \
    const short8 n0a = LDB(((s) + 1) & 7, 0);                                  \
    const short8 n0b = LDB(((s) + 1) & 7, 1);                                  \
    const short8 rA = as_s8(ringA[s][0]);                                      \
    const short8 rB = as_s8(ringA[s][1]);                                      \
    a0[0][0] = __builtin_amdgcn_mfma_f32_16x16x32_bf16(rA, f0a, a0[0][0], 0, 0, 0); \
    a0[0][1] = __builtin_amdgcn_mfma_f32_16x16x32_bf16(rA, f0b, a0[0][1], 0, 0, 0); \
    a0[1][0] = __builtin_amdgcn_mfma_f32_16x16x32_bf16(rB, f0a, a0[1][0], 0, 0, 0); \
    a0[1][1] = __builtin_amdgcn_mfma_f32_16x16x32_bf16(rB, f0b, a0[1][1], 0, 0, 0); \
    a1[0][0] = __builtin_amdgcn_mfma_f32_16x16x32_bf16(rA, wi1r[s][0], a1[0][0], 0, 0, 0); \
    a1[0][1] = __builtin_amdgcn_mfma_f32_16x16x32_bf16(rA, wi1r[s][1], a1[0][1], 0, 0, 0); \
    a1[1][0] = __builtin_amdgcn_mfma_f32_16x16x32_bf16(rB, wi1r[s][0], a1[1][0], 0, 0, 0); \
    a1[1][1] = __builtin_amdgcn_mfma_f32_16x16x32_bf16(rB, wi1r[s][1], a1[1][1], 0, 0, 0); \
    f0a = n0a; f0b = n0b;                                                      \
  }

#define STAGE_A2(s)                                                            \
  {                                                                            \
    const short8 rA = as_s8(ringB[s][0]);                                      \
    const short8 rB = as_s8(ringB[s][1]);                                      \
    a1[0][0] = __builtin_amdgcn_mfma_f32_16x16x32_bf16(rA, wh1r[s][0], a1[0][0], 0, 0, 0); \
    a1[0][1] = __builtin_amdgcn_mfma_f32_16x16x32_bf16(rA, wh1r[s][1], a1[0][1], 0, 0, 0); \
    a1[1][0] = __builtin_amdgcn_mfma_f32_16x16x32_bf16(rB, wh1r[s][0], a1[1][0], 0, 0, 0); \
    a1[1][1] = __builtin_amdgcn_mfma_f32_16x16x32_bf16(rB, wh1r[s][1], a1[1][1], 0, 0, 0); \
  }

  uint32x4 ringA[8][2];   // P0 ring: h0(slot k), issued mid-previous-tick
  uint32x4 ringB[8][2];   // P1 ring: h1(slot k-1), issued at tick start

  // prologue: issue P0 ring for slot 0 (zeroed -> clean on first scan)
  {
    const unsigned short* pa = h0r + ro0;
    const unsigned short* pb = h0r + ro1;
    ISSUE_RING(ringA, pa, pb)
  }

  for (int k = 0; k <= TT; ++k) {
    const unsigned short* pa0 = h0r + (size_t)k * SLOT + ro0;   // slot k
    const unsigned short* pb0 = h0r + (size_t)k * SLOT + ro1;
    const unsigned short* pa1 = hs + (size_t)(k > 0 ? (k - 1) : 0) * SLOT + ro0;
    const unsigned short* pb1 = hs + (size_t)(k > 0 ? (k - 1) : 0) * SLOT + ro1;

    // step 1: issue P1 ring (slot k-1) — flies under P0 scan + A01 + gates0
    ISSUE_RING(ringB, pa1, pb1)

    // step 2: wait P0 ring (P1 ring is the 16 newest; everything older —
    // ringA, wave0's h0/h1 stores, prefetch loads — gets drained). ringA
    // was issued mid-previous-tick, so its flight is already covered.
    WAITI(16)

    // step 3: scan/retry P0
    SCANLOOP(ringA, pa0, pb0)

    f32x4 a0[2][2], a1[2][2];
#pragma unroll
    for (int mt = 0; mt < 2; ++mt)
#pragma unroll
      for (int nt = 0; nt < 2; ++nt) {
        a0[mt][nt] = f32x4{0.f, 0.f, 0.f, 0.f};
        a1[mt][nt] = f32x4{0.f, 0.f, 0.f, 0.f};
      }

    // A01 MFMAs
    {
      short8 f0a = LDB(0, 0), f0b = LDB(0, 1);
      STAGE_A01(0) STAGE_A01(1) STAGE_A01(2) STAGE_A01(3)
      STAGE_A01(4) STAGE_A01(5) STAGE_A01(6) STAGE_A01(7)
    }

    // zbuf0 write + layer0 gates
    {
      const int colb = lane & 15;
      const int r0w = (lane >> 4) * 4;
#pragma unroll
      for (int mt = 0; mt < 2; ++mt)
#pragma unroll
        for (int nt = 0; nt < 2; ++nt)
#pragma unroll
          for (int r = 0; r < 4; ++r)
            zbuf[0][w][mt * 16 + r0w + r][nt * 16 + colb] = a0[mt][nt][r];
    }
    __syncthreads();
    {
      float z0[4] = {0.f, 0.f, 0.f, 0.f};
#pragma unroll
      for (int ww = 0; ww < 4; ++ww) {
        const float4 pv = *(const float4*)(&zbuf[0][ww][ebl][eu * 4]);
        z0[0] += pv.x; z0[1] += pv.y; z0[2] += pv.z; z0[3] += pv.w;
      }
      if (k < TT) {
        const float gi = sigf(z0[0] + p_pf.x);
        const float gf = sigf(z0[1] + p_pf.y);
        const float gc = tanhfast(z0[2] + p_pf.z);
        const float go = sigf(z0[3] + p_pf.w);
        c0 = gf * c0 + gi * gc;
        hstage[0][ebl * 8 + eu] = f2bf(go * tanhfast(c0));
      }
    }
    __syncthreads();

    // step 5: wave0 issues h0(k+1) full-line stores (no drain)
    if (w == 0 && k < TT && lane < 32) {
      unsigned short* dst = h0r + (size_t)(k + 1) * SLOT + g * GREG + ub * 256 + lane * 8;
      const uint32x4 val = *(const uint32x4*)&hstage[0][lane * 8];
      asm volatile("global_store_dwordx4 %0, %1, off sc0 sc1"
                   :: "v"(dst), "v"(val) : "memory");
    }

    // step 6: wait P1 ring (issued at tick start — flight covered by A01+
    // gates0). wave0: vmcnt(1) leaves its h0 store; others: vmcnt(0).
    if (w == 0) { WAITI(1) } else { WAITI(0) }
    SCANLOOP(ringB, pa1, pb1)

    // step 6.5 (MOVED EARLIER): issue P0 ring for slot k+1 — its flight now
    // hides under A2 + zbuf1/gates1 + h1-store + next tick's step-1 issue.
    // Producers' h0(k+1) stores went out at step 5 (ours and, skew-bounded,
    // everyone's): first-scan poison stays rare.
    if (k < TT) {
      const unsigned short* na = h0r + (size_t)(k + 1) * SLOT + ro0;
      const unsigned short* nb = h0r + (size_t)(k + 1) * SLOT + ro1;
      ISSUE_RING(ringA, na, nb)
    }

    // A2 MFMAs
    STAGE_A2(0) STAGE_A2(1) STAGE_A2(2) STAGE_A2(3)
    STAGE_A2(4) STAGE_A2(5) STAGE_A2(6) STAGE_A2(7)

    // zbuf1 write + layer1 gates (+ next-tick idx/P0p prefetch)
    {
      const int colb = lane & 15;
      const int r0w = (lane >> 4) * 4;
#pragma unroll
      for (int mt = 0; mt < 2; ++mt)
#pragma unroll
        for (int nt = 0; nt < 2; ++nt)
#pragma unroll
          for (int r = 0; r < 4; ++r)
            zbuf[1][w][mt * 16 + r0w + r][nt * 16 + colb] = a1[mt][nt][r];
    }
    __syncthreads();
    if (k + 1 < TT) {   // prefetch next tick's gate inputs (drained at the
      v_pf = idx[ebg * TT + k + 1];            // next tick's step-2 WAITI(16))
      p_pf = *(const float4*)(P0p + ((size_t)v_pf * HH + egu) * 4);
    }
    if (k > 0) {
      float z1[4] = {0.f, 0.f, 0.f, 0.f};
#pragma unroll
      for (int ww = 0; ww < 4; ++ww) {
        const float4 pv = *(const float4*)(&zbuf[1][ww][ebl][eu * 4]);
        z1[0] += pv.x; z1[1] += pv.y; z1[2] += pv.z; z1[3] += pv.w;
      }
      const float gi = sigf(z1[0] + b1v.x);
      const float gf = sigf(z1[1] + b1v.y);
      const float gc = tanhfast(z1[2] + b1v.z);
      const float go = sigf(z1[3] + b1v.w);
      c1 = gf * c1 + gi * gc;
      hstage[1][ebl * 8 + eu] = f2bf(go * tanhfast(c1));
    }
    __syncthreads();

    // step 9: wave0 issues h1(k) full-line stores (no drain)
    if (w == 0 && k > 0 && lane < 32) {
      unsigned short* dst = hs + (size_t)k * SLOT + g * GREG + ub * 256 + lane * 8;
      const uint32x4 val = *(const uint32x4*)&hstage[1][lane * 8];
      asm volatile("global_store_dwordx4 %0, %1, off sc0 sc1"
                   :: "v"(dst), "v"(val) : "memory");
    }
  }

  // drain final h1 stores before endpgm (proj_kernel consumes them)
  asm volatile("s_waitcnt vmcnt(0)" ::: "memory");
#undef GLDP
#undef WAITI
#undef LDB
#undef ISSUE_RING
#undef CHKR
#undef REISS
#undef SCANLOOP
#undef STAGE_A01
#undef STAGE_A2
}

// ---------------------------------------------------------------------------
// Final projection: logits[b][t][v] = hs1[b][t][:] @ Wproj.  One block per t.
// Reads hs in the regioned layout.
// ---------------------------------------------------------------------------
__global__ void __launch_bounds__(256, 1)
proj_kernel(const unsigned short* __restrict__ hs, const unsigned short* __restrict__ Wppk,
            float* __restrict__ out)
{
  __shared__ short blds[16][64][8];  // 16 KB
  const int tid = threadIdx.x;
  const int lane = tid & 63;
  const int w = tid >> 6;
  const int t = blockIdx.x;
  const unsigned short* A = hs + (size_t)(t + 1) * SLOT;
  f32x4 acc[16];
#pragma unroll
  for (int nt = 0; nt < 16; ++nt) acc[nt] = f32x4{0.f, 0.f, 0.f, 0.f};
  const int brow = w * 16 + (lane & 15);          // batch 0..63
  const int gp = brow >> 5;
  const int bl = brow & 31;
  const int aoff = gp * GREG + (lane >> 4) * 256 + bl * 8;
  for (int kt = 0; kt < 32; ++kt) {
    __syncthreads();
    for (int i = tid; i < 16 * 64; i += 256)
      *(short8*)(&blds[i >> 6][i & 63][0]) =
          *(const short8*)(Wppk + (size_t)(((i >> 6) * 32 + kt) * 64 + (i & 63)) * 8);
    __syncthreads();
    const short8 a = *(const short8*)(A + aoff + kt * 1024);
#pragma unroll
    for (int nt = 0; nt < 16; ++nt) {
      const short8 bf = *(const short8*)(&blds[nt][lane][0]);
      acc[nt] = __builtin_amdgcn_mfma_f32_16x16x32_bf16(a, bf, acc[nt], 0, 0, 0);
    }
  }
#pragma unroll
  for (int nt = 0; nt < 16; ++nt) {
#pragma unroll
    for (int r = 0; r < 4; ++r) {
      const int bbv = w * 16 + (lane >> 4) * 4 + r;
      const int vv = nt * 16 + (lane & 15);
      out[((size_t)bbv * TT + t) * VV + vv] = acc[nt][r];
    }
  }
}

// ---------------------------------------------------------------------------
extern "C" void kernel_launch(void* const* d_in, const int* in_sizes, int n_in,
                              void* d_out, int out_size, void* d_ws, size_t ws_size,
                              hipStream_t stream)
{
  (void)in_sizes; (void)n_in; (void)out_size; (void)ws_size;
  const int* idx = (const int*)d_in[0];
  const float* embed = (const float*)d_in[1];
  const float* Wi = (const float*)d_in[2];
  const float* Wh = (const float*)d_in[3];
  const float* bias = (const float*)d_in[4];
  const float* Wproj = (const float*)d_in[5];
  float* out = (float*)d_out;

  char* ws = (char*)d_ws;
  size_t off = 0;
  unsigned short* h0r = (unsigned short*)(ws + off); off += 513ull * SLOT * 2;        // ~64.1 MB
  unsigned short* hs = (unsigned short*)(ws + off);  off += 513ull * SLOT * 2;        // ~64.1 MB
  float* P0p = (float*)(ws + off);                  off += 256ull * HH * 4 * 4;       // 4 MB
  unsigned short* Wppk = (unsigned short*)(ws + off); off += 16ull * 32 * 64 * 8 * 2; // 512 KB
  float* b1p = (float*)(ws + off);                  off += 4096ull * 4;

  // poison h buffers (0xFFFF u16 = bf16 NaN, unreachable for tanh outputs);
  // slot 0 of each = initial state = 0
  hipMemsetAsync(h0r, 0xFF, 513ull * SLOT * 2, stream);
  hipMemsetAsync(hs, 0xFF, 513ull * SLOT * 2, stream);
  hipMemsetAsync(h0r, 0, (size_t)SLOT * 2, stream);
  hipMemsetAsync(hs, 0, (size_t)SLOT * 2, stream);

  p0_kernel<<<256, 256, 0, stream>>>(embed, Wi, bias, P0p);
  pack_misc<<<128, 256, 0, stream>>>(Wproj, bias, Wppk, b1p);

  lstm_persist<<<NBLK, 256, 0, stream>>>(Wi, Wh, idx, P0p, b1p, h0r, hs);

  proj_kernel<<<512, 256, 0, stream>>>(hs, Wppk, out);
}

// Round 21
// 2223.140 us; speedup vs baseline: 1.3086x; 1.3086x over previous
//
#include <hip/hip_runtime.h>

#define BB 64
#define HH 1024
#define TT 512
#define GG 4096
#define VV 256
#define NBLK 256
#define BPG 128   // blocks per group
#define BG  32    // batches per group
#define UPB 8     // units per block
#define SLOT (BB * HH)        // 65536 elements per h slot
#define GREG 32768            // elements per group region within a slot

typedef __attribute__((ext_vector_type(8))) short short8;
typedef __attribute__((ext_vector_type(4))) float f32x4;
typedef __attribute__((ext_vector_type(4))) unsigned uint32x4;

__device__ __forceinline__ unsigned short f2bf(float f) {
  unsigned u = __float_as_uint(f);
  u += 0x7fffu + ((u >> 16) & 1u);
  return (unsigned short)(u >> 16);
}

__device__ __forceinline__ float sigf(float x) { return 1.0f / (1.0f + __expf(-x)); }
__device__ __forceinline__ float tanhfast(float x) {
  float t = __expf(2.0f * x);
  return (t - 1.0f) / (t + 1.0f);
}

__device__ __forceinline__ unsigned pkmax(unsigned a, unsigned b) {
  unsigned d;
  asm("v_pk_max_u16 %0, %1, %2" : "=v"(d) : "v"(a), "v"(b));
  return d;
}

__device__ __forceinline__ bool anypoison(uint32x4 a, uint32x4 b) {
  const unsigned mm = pkmax(pkmax(pkmax(a[0], a[1]), pkmax(a[2], a[3])),
                            pkmax(pkmax(b[0], b[1]), pkmax(b[2], b[3])));
  return ((mm & 0xFFFFu) == 0xFFFFu) || ((mm >> 16) == 0xFFFFu);
}

__device__ __forceinline__ short8 as_s8(uint32x4 v) {
  short8 r;
  __builtin_memcpy(&r, &v, 16);
  return r;
}

// ---------------------------------------------------------------------------
// Prepass 1: P0[v][unit][gate] = (embed @ Wi[0] + b[0]) re-packed, fp32.
// ---------------------------------------------------------------------------
__global__ void __launch_bounds__(256, 1)
p0_kernel(const float* __restrict__ embed, const float* __restrict__ Wi,
          const float* __restrict__ bias, float* __restrict__ P0p)
{
  __shared__ float elds[16][1024];  // 64 KB
  const int tid = threadIdx.x;
  const int vt = blockIdx.x >> 4;
  const int ct = blockIdx.x & 15;
  for (int i = tid; i < 16 * 1024; i += 256)
    elds[i >> 10][i & 1023] = embed[((vt * 16 + (i >> 10)) << 10) + (i & 1023)];
  __syncthreads();
  const int c = ct * 256 + tid;           // column in [0,4096)
  float acc[16];
#pragma unroll
  for (int v = 0; v < 16; ++v) acc[v] = 0.f;
  for (int kk = 0; kk < 1024; ++kk) {
    const float wv = Wi[kk * GG + c];     // coalesced
#pragma unroll
    for (int v = 0; v < 16; ++v) acc[v] = fmaf(elds[v][kk], wv, acc[v]);
  }
  const int u = c & 1023, g = c >> 10;
  const float bv = bias[c];               // b[0][c]
#pragma unroll
  for (int v = 0; v < 16; ++v)
    P0p[(((size_t)(vt * 16 + v) * HH) + u) * 4 + g] = acc[v] + bv;
}

// ---------------------------------------------------------------------------
// Prepass 2: pack Wproj into bf16 MFMA B-fragments; pack b[1] as [unit][gate].
// ---------------------------------------------------------------------------
__global__ void pack_misc(const float* __restrict__ Wproj, const float* __restrict__ bias,
                          unsigned short* __restrict__ Wppk, float* __restrict__ b1p)
{
  const int t = blockIdx.x * 256 + threadIdx.x;
  if (t < 16 * 32 * 64) {
    const int lane = t & 63;
    const int kt = (t >> 6) & 31;
    const int nt = t >> 11;
    const int v = nt * 16 + (lane & 15);
    const int kb = kt * 32 + (lane >> 4) * 8;
    short8 fr;
#pragma unroll
    for (int e = 0; e < 8; ++e)
      fr[e] = (short)f2bf(Wproj[(size_t)(kb + e) * VV + v]);
    *(short8*)(Wppk + (size_t)t * 8) = fr;
  }
  if (t < 4096)
    b1p[t] = bias[GG + (t & 3) * HH + (t >> 2)];  // b1p[u*4+g] = b[1][g*1024+u]
}

// ---------------------------------------------------------------------------
// Persistent LSTM kernel (round-18 best configuration, reverted):
// split-phase data-poll + pipelined ring issue. ringB (h1, slot k-1) issued
// at tick start (flies under P0 scan + A01 + gates0); ringA (h0, slot k+1)
// issued at tick END (after all producers' step-5 stores). Initial loads
// cached (equivalent to bypass, measured); retries bypass L2 (sc0 sc1).
// Poison protocol: h rotates write-once, pre-poisoned 0xFFFF (bf16 NaN,
// unreachable for |tanh|<1 outputs). REGIONED layout (r13): full-line
// single-producer write-through stores from wave 0.
// ---------------------------------------------------------------------------
__global__ void __launch_bounds__(256, 1)
lstm_persist(const float* __restrict__ Wi, const float* __restrict__ Wh,
             const int* __restrict__ idx, const float* __restrict__ P0p,
             const float* __restrict__ b1p,
             unsigned short* __restrict__ h0r, unsigned short* __restrict__ hs)
{
  __shared__ short wlds[32][2][64][8];      // 64 KB: Wh0 [kt][nt][lane][8]
  __shared__ float zbuf[2][4][32][36];      // 36 KB
  __shared__ unsigned short hstage[2][256]; // 1 KB

  const int tid = threadIdx.x;
  const int lane = tid & 63;
  const int w = tid >> 6;
  const int bid = blockIdx.x;
  const int g = bid & 1;          // group (~XCD parity)
  const int ub = bid >> 1;        // unit-block 0..127
  const int w8 = w * 8;

  // ---- one-time: Wh0 fragments -> LDS; Wi1, Wh1 fragments -> VGPRs ----
  short8 wi1r[8][2], wh1r[8][2];
  {
    const int arow16 = lane & 15;
    const int kb4 = (lane >> 4) * 8;
    for (int kk = 0; kk < 8; ++kk) {
      const int kbase = (w8 + kk) * 32 + kb4;
      for (int nt = 0; nt < 2; ++nt) {
        const int cl = nt * 16 + arow16;
        const int cg = (cl & 3) * HH + ub * UPB + (cl >> 2);
        short8 fr;
#pragma unroll
        for (int e = 0; e < 8; ++e)
          fr[e] = (short)f2bf(Wh[(size_t)(kbase + e) * GG + cg]);
        *(short8*)(&wlds[w8 + kk][nt][lane][0]) = fr;
      }
    }
    const float* srcWi1 = Wi + (size_t)HH * GG;
    const float* srcWh1 = Wh + (size_t)HH * GG;
#pragma unroll
    for (int kk = 0; kk < 8; ++kk) {
      const int kbase = (w8 + kk) * 32 + kb4;
#pragma unroll
      for (int nt = 0; nt < 2; ++nt) {
        const int cl = nt * 16 + arow16;
        const int cg = (cl & 3) * HH + ub * UPB + (cl >> 2);
        short8 fa, fb;
#pragma unroll
        for (int e = 0; e < 8; ++e) {
          fa[e] = (short)f2bf(srcWi1[(size_t)(kbase + e) * GG + cg]);
          fb[e] = (short)f2bf(srcWh1[(size_t)(kbase + e) * GG + cg]);
        }
        wi1r[kk][nt] = fa;
        wh1r[kk][nt] = fb;
      }
    }
  }
  __syncthreads();

  const int ebl = tid >> 3;            // 0..31
  const int eu = tid & 7;              // 0..7
  const int ebg = g * BG + ebl;        // global batch row
  const int egu = ub * UPB + eu;       // global unit
  float c0 = 0.f, c1 = 0.f;
  const float4 b1v = *(const float4*)(b1p + egu * 4);

  const int arow = lane & 15;
  // regioned A offsets within a slot (r13 layout)
  const int ro0 = g * GREG + w8 * 1024 + (lane >> 4) * 256 + arow * 8;
  const int ro1 = ro0 + 128;

  int v_pf = idx[ebg * TT];                                        // k = 0
  float4 p_pf = *(const float4*)(P0p + ((size_t)v_pf * HH + egu) * 4);

// cached load (initial issue; stale copy can only be poison -> detectable)
#define GLDC(dst, addr)                                                        \
  asm volatile("global_load_dwordx4 %0, %1, off"                               \
               : "=&v"(dst) : "v"(addr));
// bypass load (retry path: always fresh at L3)
#define GLDP(dst, addr)                                                        \
  asm volatile("global_load_dwordx4 %0, %1, off sc0 sc1"                       \
               : "=&v"(dst) : "v"(addr));

#define WAITI(n)                                                               \
  asm volatile("s_waitcnt vmcnt(" #n ")" ::: "memory");                        \
  __builtin_amdgcn_sched_barrier(0);

#define LDB(s, nt) (*(const short8*)(&wlds[w8 + (s)][nt][lane][0]))

#define ISSUE_RING(rg, pa, pb)                                                 \
  GLDC(rg[0][0], (pa) + 0 * 1024) GLDC(rg[0][1], (pb) + 0 * 1024)              \
  GLDC(rg[1][0], (pa) + 1 * 1024) GLDC(rg[1][1], (pb) + 1 * 1024)              \
  GLDC(rg[2][0], (pa) + 2 * 1024) GLDC(rg[2][1], (pb) + 2 * 1024)              \
  GLDC(rg[3][0], (pa) + 3 * 1024) GLDC(rg[3][1], (pb) + 3 * 1024)              \
  GLDC(rg[4][0], (pa) + 4 * 1024) GLDC(rg[4][1], (pb) + 4 * 1024)              \
  GLDC(rg[5][0], (pa) + 5 * 1024) GLDC(rg[5][1], (pb) + 5 * 1024)              \
  GLDC(rg[6][0], (pa) + 6 * 1024) GLDC(rg[6][1], (pb) + 6 * 1024)              \
  GLDC(rg[7][0], (pa) + 7 * 1024) GLDC(rg[7][1], (pb) + 7 * 1024)

#define CHKR(rg, s)                                                            \
  if (need & (1u << (s))) {                                                    \
    if (__any(anypoison(rg[s][0], rg[s][1]))) nneed |= (1u << (s));            \
  }

#define REISS(rg, s, pa, pb)                                                   \
  if (need & (1u << (s))) {                                                    \
    GLDP(rg[s][0], (pa) + (s) * 1024)                                          \
    GLDP(rg[s][1], (pb) + (s) * 1024)                                          \
  }

// initial scan + bounded retry loop (retries bypass L2 and drain: vmcnt(0))
#define SCANLOOP(rg, pa, pb)                                                   \
  {                                                                            \
    unsigned need = 0xFFu;                                                     \
    {                                                                          \
      unsigned nneed = 0;                                                      \
      CHKR(rg, 0) CHKR(rg, 1) CHKR(rg, 2) CHKR(rg, 3)                          \
      CHKR(rg, 4) CHKR(rg, 5) CHKR(rg, 6) CHKR(rg, 7)                          \
      need = nneed;                                                            \
    }                                                                          \
    int tries = 0;                                                             \
    while (need) {                                                             \
      if (++tries > (1 << 17)) break;  /* safety valve */                      \
      __builtin_amdgcn_s_sleep(4);                                             \
      REISS(rg, 0, pa, pb) REISS(rg, 1, pa, pb) REISS(rg, 2, pa, pb)           \
      REISS(rg, 3, pa, pb) REISS(rg, 4, pa, pb) REISS(rg, 5, pa, pb)           \
      REISS(rg, 6, pa, pb) REISS(rg, 7, pa, pb)                                \
      WAITI(0)                                                                 \
      unsigned nneed = 0;                                                      \
      CHKR(rg, 0) CHKR(rg, 1) CHKR(rg, 2) CHKR(rg, 3)                          \
      CHKR(rg, 4) CHKR(rg, 5) CHKR(rg, 6) CHKR(rg, 7)                          \
      need = nneed;                                                            \
    }                                                                          \
    __builtin_amdgcn_sched_barrier(0);                                         \
  }

#define STAGE_A01(s)                                                           \
  {                                                                            \
    const short8 n0a = LDB(((s) + 1) & 7, 0);                                  \
    const short8 n0b = LDB(((s) + 1) & 7, 1);                                  \
    const short8 rA = as_s8(ringA[s][0]);                                      \
    const short8 rB = as_s8(ringA[s][1]);                                      \
    a0[0][0] = __builtin_amdgcn_mfma_f32_16x16x32_bf16(rA, f0a, a0[0][0], 0, 0, 0); \
    a0[0][1] = __builtin_amdgcn_mfma_f32_16x16x32_bf16(rA, f0b, a0[0][1], 0, 0, 0); \
    a0[1][0] = __builtin_amdgcn_mfma_f32_16x16x32_bf16(rB, f0a, a0[1][0], 0, 0, 0); \
    a0[1][1] = __builtin_amdgcn_mfma_f32_16x16x32_bf16(rB, f0b, a0[1][1], 0, 0, 0); \
    a1[0][0] = __builtin_amdgcn_mfma_f32_16x16x32_bf16(rA, wi1r[s][0], a1[0][0], 0, 0, 0); \
    a1[0][1] = __builtin_amdgcn_mfma_f32_16x16x32_bf16(rA, wi1r[s][1], a1[0][1], 0, 0, 0); \
    a1[1][0] = __builtin_amdgcn_mfma_f32_16x16x32_bf16(rB, wi1r[s][0], a1[1][0], 0, 0, 0); \
    a1[1][1] = __builtin_amdgcn_mfma_f32_16x16x32_bf16(rB, wi1r[s][1], a1[1][1], 0, 0, 0); \
    f0a = n0a; f0b = n0b;                                                      \
  }

#define STAGE_A2(s)                                                            \
  {                                                                            \
    const short8 rA = as_s8(ringB[s][0]);                                      \
    const short8 rB = as_s8(ringB[s][1]);                                      \
    a1[0][0] = __builtin_amdgcn_mfma_f32_16x16x32_bf16(rA, wh1r[s][0], a1[0][0], 0, 0, 0); \
    a1[0][1] = __builtin_amdgcn_mfma_f32_16x16x32_bf16(rA, wh1r[s][1], a1[0][1], 0, 0, 0); \
    a1[1][0] = __builtin_amdgcn_mfma_f32_16x16x32_bf16(rB, wh1r[s][0], a1[1][0], 0, 0, 0); \
    a1[1][1] = __builtin_amdgcn_mfma_f32_16x16x32_bf16(rB, wh1r[s][1], a1[1][1], 0, 0, 0); \
  }

  uint32x4 ringA[8][2];   // P0 ring: h0(slot k), issued one phase ahead
  uint32x4 ringB[8][2];   // P1 ring: h1(slot k-1), issued at tick start

  // prologue: issue P0 ring for slot 0 (zeroed -> clean on first scan)
  {
    const unsigned short* pa = h0r + ro0;
    const unsigned short* pb = h0r + ro1;
    ISSUE_RING(ringA, pa, pb)
  }

  for (int k = 0; k <= TT; ++k) {
    const unsigned short* pa0 = h0r + (size_t)k * SLOT + ro0;   // slot k
    const unsigned short* pb0 = h0r + (size_t)k * SLOT + ro1;
    const unsigned short* pa1 = hs + (size_t)(k > 0 ? (k - 1) : 0) * SLOT + ro0;
    const unsigned short* pb1 = hs + (size_t)(k > 0 ? (k - 1) : 0) * SLOT + ro1;

    // step 1: issue P1 ring (slot k-1) — flies under P0 scan + A01 + gates0
    ISSUE_RING(ringB, pa1, pb1)

    // step 2: wait P0 ring (P1 ring is the 16 newest; everything older —
    // P0 ring, wave0's h1 store, prefetch loads — gets drained)
    WAITI(16)

    // step 3: scan/retry P0
    SCANLOOP(ringA, pa0, pb0)

    f32x4 a0[2][2], a1[2][2];
#pragma unroll
    for (int mt = 0; mt < 2; ++mt)
#pragma unroll
      for (int nt = 0; nt < 2; ++nt) {
        a0[mt][nt] = f32x4{0.f, 0.f, 0.f, 0.f};
        a1[mt][nt] = f32x4{0.f, 0.f, 0.f, 0.f};
      }

    // A01 MFMAs
    {
      short8 f0a = LDB(0, 0), f0b = LDB(0, 1);
      STAGE_A01(0) STAGE_A01(1) STAGE_A01(2) STAGE_A01(3)
      STAGE_A01(4) STAGE_A01(5) STAGE_A01(6) STAGE_A01(7)
    }

    // zbuf0 write + layer0 gates
    {
      const int colb = lane & 15;
      const int r0w = (lane >> 4) * 4;
#pragma unroll
      for (int mt = 0; mt < 2; ++mt)
#pragma unroll
        for (int nt = 0; nt < 2; ++nt)
#pragma unroll
          for (int r = 0; r < 4; ++r)
            zbuf[0][w][mt * 16 + r0w + r][nt * 16 + colb] = a0[mt][nt][r];
    }
    __syncthreads();
    {
      float z0[4] = {0.f, 0.f, 0.f, 0.f};
#pragma unroll
      for (int ww = 0; ww < 4; ++ww) {
        const float4 pv = *(const float4*)(&zbuf[0][ww][ebl][eu * 4]);
        z0[0] += pv.x; z0[1] += pv.y; z0[2] += pv.z; z0[3] += pv.w;
      }
      if (k < TT) {
        const float gi = sigf(z0[0] + p_pf.x);
        const float gf = sigf(z0[1] + p_pf.y);
        const float gc = tanhfast(z0[2] + p_pf.z);
        const float go = sigf(z0[3] + p_pf.w);
        c0 = gf * c0 + gi * gc;
        hstage[0][ebl * 8 + eu] = f2bf(go * tanhfast(c0));
        if (k + 1 < TT) {   // foreign prefetch loads (older than next rings)
          v_pf = idx[ebg * TT + k + 1];
          p_pf = *(const float4*)(P0p + ((size_t)v_pf * HH + egu) * 4);
        }
      }
    }
    __syncthreads();

    // step 5: wave0 issues h0(k+1) full-line stores (no drain)
    if (w == 0 && k < TT && lane < 32) {
      unsigned short* dst = h0r + (size_t)(k + 1) * SLOT + g * GREG + ub * 256 + lane * 8;
      const uint32x4 val = *(const uint32x4*)&hstage[0][lane * 8];
      asm volatile("global_store_dwordx4 %0, %1, off sc0 sc1"
                   :: "v"(dst), "v"(val) : "memory");
    }

    // step 6: wait P1 ring (issued at tick start — mostly already returned).
    // wave0: vmcnt(1) leaves its h0 store in flight; others: vmcnt(0).
    if (w == 0) { WAITI(1) } else { WAITI(0) }
    SCANLOOP(ringB, pa1, pb1)

    // A2 MFMAs
    STAGE_A2(0) STAGE_A2(1) STAGE_A2(2) STAGE_A2(3)
    STAGE_A2(4) STAGE_A2(5) STAGE_A2(6) STAGE_A2(7)

    // zbuf1 write + layer1 gates
    {
      const int colb = lane & 15;
      const int r0w = (lane >> 4) * 4;
#pragma unroll
      for (int mt = 0; mt < 2; ++mt)
#pragma unroll
        for (int nt = 0; nt < 2; ++nt)
#pragma unroll
          for (int r = 0; r < 4; ++r)
            zbuf[1][w][mt * 16 + r0w + r][nt * 16 + colb] = a1[mt][nt][r];
    }
    __syncthreads();
    if (k > 0) {
      float z1[4] = {0.f, 0.f, 0.f, 0.f};
#pragma unroll
      for (int ww = 0; ww < 4; ++ww) {
        const float4 pv = *(const float4*)(&zbuf[1][ww][ebl][eu * 4]);
        z1[0] += pv.x; z1[1] += pv.y; z1[2] += pv.z; z1[3] += pv.w;
      }
      const float gi = sigf(z1[0] + b1v.x);
      const float gf = sigf(z1[1] + b1v.y);
      const float gc = tanhfast(z1[2] + b1v.z);
      const float go = sigf(z1[3] + b1v.w);
      c1 = gf * c1 + gi * gc;
      hstage[1][ebl * 8 + eu] = f2bf(go * tanhfast(c1));
    }
    __syncthreads();

    // step 9: wave0 issues h1(k) full-line stores (no drain)
    if (w == 0 && k > 0 && lane < 32) {
      unsigned short* dst = hs + (size_t)k * SLOT + g * GREG + ub * 256 + lane * 8;
      const uint32x4 val = *(const uint32x4*)&hstage[1][lane * 8];
      asm volatile("global_store_dwordx4 %0, %1, off sc0 sc1"
                   :: "v"(dst), "v"(val) : "memory");
    }

    // step 10: issue P0 ring for slot k+1 — after ALL producers' step-5
    // stores (skew-safe); flies across the tick boundary
    if (k < TT) {
      const unsigned short* na = h0r + (size_t)(k + 1) * SLOT + ro0;
      const unsigned short* nb = h0r + (size_t)(k + 1) * SLOT + ro1;
      ISSUE_RING(ringA, na, nb)
    }
  }

  // drain final h1 stores before endpgm (proj_kernel consumes them)
  asm volatile("s_waitcnt vmcnt(0)" ::: "memory");
#undef GLDC
#undef GLDP
#undef WAITI
#undef LDB
#undef ISSUE_RING
#undef CHKR
#undef REISS
#undef SCANLOOP
#undef STAGE_A01
#undef STAGE_A2
}

// ---------------------------------------------------------------------------
// Final projection: logits[b][t][v] = hs1[b][t][:] @ Wproj.  One block per t.
// Reads hs in the regioned layout.
// ---------------------------------------------------------------------------
__global__ void __launch_bounds__(256, 1)
proj_kernel(const unsigned short* __restrict__ hs, const unsigned short* __restrict__ Wppk,
            float* __restrict__ out)
{
  __shared__ short blds[16][64][8];  // 16 KB
  const int tid = threadIdx.x;
  const int lane = tid & 63;
  const int w = tid >> 6;
  const int t = blockIdx.x;
  const unsigned short* A = hs + (size_t)(t + 1) * SLOT;
  f32x4 acc[16];
#pragma unroll
  for (int nt = 0; nt < 16; ++nt) acc[nt] = f32x4{0.f, 0.f, 0.f, 0.f};
  const int brow = w * 16 + (lane & 15);          // batch 0..63
  const int gp = brow >> 5;
  const int bl = brow & 31;
  const int aoff = gp * GREG + (lane >> 4) * 256 + bl * 8;
  for (int kt = 0; kt < 32; ++kt) {
    __syncthreads();
    for (int i = tid; i < 16 * 64; i += 256)
      *(short8*)(&blds[i >> 6][i & 63][0]) =
          *(const short8*)(Wppk + (size_t)(((i >> 6) * 32 + kt) * 64 + (i & 63)) * 8);
    __syncthreads();
    const short8 a = *(const short8*)(A + aoff + kt * 1024);
#pragma unroll
    for (int nt = 0; nt < 16; ++nt) {
      const short8 bf = *(const short8*)(&blds[nt][lane][0]);
      acc[nt] = __builtin_amdgcn_mfma_f32_16x16x32_bf16(a, bf, acc[nt], 0, 0, 0);
    }
  }
#pragma unroll
  for (int nt = 0; nt < 16; ++nt) {
#pragma unroll
    for (int r = 0; r < 4; ++r) {
      const int bbv = w * 16 + (lane >> 4) * 4 + r;
      const int vv = nt * 16 + (lane & 15);
      out[((size_t)bbv * TT + t) * VV + vv] = acc[nt][r];
    }
  }
}

// ---------------------------------------------------------------------------
extern "C" void kernel_launch(void* const* d_in, const int* in_sizes, int n_in,
                              void* d_out, int out_size, void* d_ws, size_t ws_size,
                              hipStream_t stream)
{
  (void)in_sizes; (void)n_in; (void)out_size; (void)ws_size;
  const int* idx = (const int*)d_in[0];
  const float* embed = (const float*)d_in[1];
  const float* Wi = (const float*)d_in[2];
  const float* Wh = (const float*)d_in[3];
  const float* bias = (const float*)d_in[4];
  const float* Wproj = (const float*)d_in[5];
  float* out = (float*)d_out;

  char* ws = (char*)d_ws;
  size_t off = 0;
  unsigned short* h0r = (unsigned short*)(ws + off); off += 513ull * SLOT * 2;        // ~64.1 MB
  unsigned short* hs = (unsigned short*)(ws + off);  off += 513ull * SLOT * 2;        // ~64.1 MB
  float* P0p = (float*)(ws + off);                  off += 256ull * HH * 4 * 4;       // 4 MB
  unsigned short* Wppk = (unsigned short*)(ws + off); off += 16ull * 32 * 64 * 8 * 2; // 512 KB
  float* b1p = (float*)(ws + off);                  off += 4096ull * 4;

  // poison h buffers (0xFFFF u16 = bf16 NaN, unreachable for tanh outputs);
  // slot 0 of each = initial state = 0
  hipMemsetAsync(h0r, 0xFF, 513ull * SLOT * 2, stream);
  hipMemsetAsync(hs, 0xFF, 513ull * SLOT * 2, stream);
  hipMemsetAsync(h0r, 0, (size_t)SLOT * 2, stream);
  hipMemsetAsync(hs, 0, (size_t)SLOT * 2, stream);

  p0_kernel<<<256, 256, 0, stream>>>(embed, Wi, bias, P0p);
  pack_misc<<<128, 256, 0, stream>>>(Wproj, bias, Wppk, b1p);

  lstm_persist<<<NBLK, 256, 0, stream>>>(Wi, Wh, idx, P0p, b1p, h0r, hs);

  proj_kernel<<<512, 256, 0, stream>>>(hs, Wppk, out);
}